// Round 4
// baseline (665.084 us; speedup 1.0000x reference)
//
#include <hip/hip_runtime.h>

#define T_LEN 2048
#define B_SZ  8192
#define H     16
#define EPSC  1e-5f
#define LOG2E 1.4426950408889634f

typedef __attribute__((ext_vector_type(4))) float f32x4;
typedef __attribute__((ext_vector_type(2))) float f32x2;
typedef __attribute__((ext_vector_type(4))) short s16x4;

__device__ __forceinline__ float fexp2(float x){ float r; asm("v_exp_f32 %0, %1" : "=v"(r) : "v"(x)); return r; }
__device__ __forceinline__ float frcp (float x){ float r; asm("v_rcp_f32 %0, %1" : "=v"(r) : "v"(x)); return r; }
__device__ __forceinline__ unsigned cvtpk_bf16(float a, float b){
    unsigned r; asm("v_cvt_pk_bf16_f32 %0, %1, %2" : "=v"(r) : "v"(a), "v"(b)); return r;
}
__device__ __forceinline__ unsigned short f2bf(float f){   // RNE f32->bf16 (init-time)
    union { float f; unsigned u; } v; v.f = f;
    return (unsigned short)((v.u + 0x7fffu + ((v.u >> 16) & 1u)) >> 16);
}
__device__ __forceinline__ float bf2f(unsigned s){
    union { unsigned u; float f; } v; v.u = s << 16; return v.f;
}

#if __has_builtin(__builtin_amdgcn_mfma_f32_16x16x16bf16_1k)
__device__ __forceinline__ f32x4 MFMA16(s16x4 a, s16x4 b, f32x4 c){
    return __builtin_amdgcn_mfma_f32_16x16x16bf16_1k(a, b, c, 0, 0, 0);
}
#else
__device__ __forceinline__ f32x4 MFMA16(s16x4 a, s16x4 b, f32x4 c){
    f32x4 d;
    asm volatile("v_mfma_f32_16x16x16_bf16 %0, %1, %2, %3\n\ts_nop 7\n\ts_nop 7"
                 : "=v"(d) : "v"(a), "v"(b), "v"(c));
    return d;
}
#endif

// ---------------- Kernel A: per-timestep partial sums of x and x^2 -----------
__global__ __launch_bounds__(256) void k_stats(const float* __restrict__ x,
                                               float* __restrict__ part_s,
                                               float* __restrict__ part_q){
    int t  = blockIdx.x * 256 + threadIdx.x;
    int b0 = blockIdx.y * 128;
    const float* xp = x + (size_t)b0 * T_LEN + t;
    float s = 0.f, q = 0.f;
    #pragma unroll 4
    for (int i = 0; i < 128; ++i){
        float v = xp[(size_t)i * T_LEN];
        s += v; q = fmaf(v, v, q);
    }
    part_s[blockIdx.y * T_LEN + t] = s;
    part_q[blockIdx.y * T_LEN + t] = q;
}

// ---------------- Kernel B: BN coefficients A_t, B_t -------------------------
__global__ __launch_bounds__(256) void k_coeff(const float* __restrict__ part_s,
                                               const float* __restrict__ part_q,
                                               const float* __restrict__ fc1_w,
                                               const float* __restrict__ bn_g,
                                               const float* __restrict__ bn_b,
                                               float2* __restrict__ AB){
    int t = blockIdx.x * 256 + threadIdx.x;
    float s = 0.f, q = 0.f;
    for (int i = 0; i < 64; ++i){
        s += part_s[i * T_LEN + t];
        q += part_q[i * T_LEN + t];
    }
    float mu  = s * (1.f / B_SZ);
    float var = fmaf(-mu, mu, q * (1.f / B_SZ));
    float w   = fc1_w[0];
    float rs  = rsqrtf(fmaf(w * w, var, EPSC));
    float A   = bn_g[0] * rs * w;
    float Bc  = bn_b[0] - A * mu;
    AB[t] = make_float2(A, Bc);
}

// ---------------- Kernel D: MFMA LSTM + fc2 + softmax ------------------------
// One wave per 16 batch rows. Per t: 4x v_mfma_f32_16x16x16_bf16 (A=W_q const,
// B=h packed bf16, C=bias+ft*w_ih). D-frag (col=lane&15,row=4g+r) == B-frag
// (col=lane&15,k=4g+e) lane-for-lane => h->B is 2 cvt_pk, no cross-lane ops.
// ft tiles (BN+ReLU) staged in LDS, double-buffered, computed during staging.
// C-init for t+1 computed during t's activation phase (1-ahead pipeline).
__global__ __launch_bounds__(64) void k_lstm(
    const float* __restrict__ x, const float2* __restrict__ AB,
    const float* __restrict__ w_ih, const float* __restrict__ w_hh,
    const float* __restrict__ b_ih, const float* __restrict__ b_hh,
    const float* __restrict__ fc2_w, const float* __restrict__ fc2_b,
    float* __restrict__ out)
{
    __shared__ float sF[2][16][68];     // ft tiles; stride 68 -> 2-way bank alias (free)

    const int lane = threadIdx.x;       // 0..63
    const int g    = lane >> 4;         // k-group / row-group
    const int jm   = lane & 15;         // A row j  ==  D/B column b
    const int b0   = blockIdx.x * 16;

    // ---- stationary A fragments: W_q[j=jm][k=4g..4g+3], prescaled, bf16 ----
    const float sc0 = -LOG2E, sc2 = 2.f * LOG2E;
    s16x4 Wq[4];
    #pragma unroll
    for (int q = 0; q < 4; ++q){
        float s = (q == 2) ? sc2 : sc0;
        const float* wr = w_hh + (q*H + jm)*H + 4*g;
        s16x4 w4;
        w4.x = (short)f2bf(wr[0]*s); w4.y = (short)f2bf(wr[1]*s);
        w4.z = (short)f2bf(wr[2]*s); w4.w = (short)f2bf(wr[3]*s);
        Wq[q] = w4;
    }
    // ---- C-init constants for rows j = 4g+r ----
    f32x2 wih2[4][2], bia2[4][2];
    #pragma unroll
    for (int q = 0; q < 4; ++q){
        float s = (q == 2) ? sc2 : sc0;
        #pragma unroll
        for (int rp = 0; rp < 2; ++rp){
            int j0 = q*H + 4*g + 2*rp;
            wih2[q][rp] = (f32x2){ w_ih[j0]*s, w_ih[j0+1]*s };
            bia2[q][rp] = (f32x2){ (b_ih[j0]+b_hh[j0])*s, (b_ih[j0+1]+b_hh[j0+1])*s };
        }
    }
    float fcw0[4], fcw1[4];
    #pragma unroll
    for (int r = 0; r < 4; ++r){
        fcw0[r] = fc2_w[      4*g + r];
        fcw1[r] = fc2_w[H   + 4*g + r];
    }

    // ---- staging helpers ----
    float4 xv[4]; float2 av[4];
    auto issue_loads = [&](int c){
        int t0 = c * 64;
        #pragma unroll
        for (int p = 0; p < 4; ++p)
            xv[p] = *(const float4*)(x + (size_t)(b0 + (lane>>4) + 4*p) * T_LEN + t0 + 4*(lane&15));
        #pragma unroll
        for (int u = 0; u < 4; ++u)
            av[u] = AB[t0 + 4*(lane&15) + u];
    };
    auto stage = [&](int buf){
        #pragma unroll
        for (int p = 0; p < 4; ++p){
            float4 f;
            f.x = fmaxf(fmaf(av[0].x, xv[p].x, av[0].y), 0.f);
            f.y = fmaxf(fmaf(av[1].x, xv[p].y, av[1].y), 0.f);
            f.z = fmaxf(fmaf(av[2].x, xv[p].z, av[2].y), 0.f);
            f.w = fmaxf(fmaf(av[3].x, xv[p].w, av[3].y), 0.f);
            *(float4*)&sF[buf][(lane>>4) + 4*p][4*(lane&15)] = f;
        }
    };

    issue_loads(0);
    stage(0);
    issue_loads(1);

    // ---- prime pipeline: cc for t=0 ----
    f32x4 ccA[4], ccB[4];
    float ft0 = sF[0][jm][0];
    #pragma unroll
    for (int q = 0; q < 4; ++q){
        f32x2 lo = wih2[q][0]*ft0 + bia2[q][0];
        f32x2 hi = wih2[q][1]*ft0 + bia2[q][1];
        ccA[q] = (f32x4){lo.x, lo.y, hi.x, hi.y};
    }

    unsigned hp0 = 0, hp1 = 0;          // h packed bf16x4 = next B operand
    float cst[4] = {0.f, 0.f, 0.f, 0.f};

    auto step = [&](f32x4* CC, f32x4* CCN, int t, const float* fb, const float* fbN){
        union { unsigned u[2]; s16x4 s; } bb; bb.u[0] = hp0; bb.u[1] = hp1;
        f32x4 d0 = MFMA16(Wq[0], bb.s, CC[0]);
        f32x4 d1 = MFMA16(Wq[1], bb.s, CC[1]);
        f32x4 d2 = MFMA16(Wq[2], bb.s, CC[2]);
        f32x4 d3 = MFMA16(Wq[3], bb.s, CC[3]);
        // --- independent: ft[t+1] + next C-init (fills MFMA/trans shadow) ---
        int tn = t + 1;
        float ftn = ((tn & 63) == 0) ? fbN[0] : fb[tn & 63];
        #pragma unroll
        for (int q = 0; q < 4; ++q){
            f32x2 lo = wih2[q][0]*ftn + bia2[q][0];
            f32x2 hi = wih2[q][1]*ftn + bia2[q][1];
            CCN[q] = (f32x4){lo.x, lo.y, hi.x, hi.y};
        }
        // --- activations for rows j = 4g + r ---
        float hr[4];
        #pragma unroll
        for (int r = 0; r < 4; ++r){
            float si = frcp(1.f + fexp2(d0[r]));
            float sf = frcp(1.f + fexp2(d1[r]));
            float tg = fmaf(-2.f, frcp(1.f + fexp2(d2[r])), 1.f);
            float so = frcp(1.f + fexp2(d3[r]));
            float cn = fmaf(sf, cst[r], si * tg);
            cst[r] = cn;
            float tc = fmaf(-2.f, frcp(1.f + fexp2(cn * (2.f*LOG2E))), 1.f);
            hr[r] = so * tc;
        }
        hp0 = cvtpk_bf16(hr[0], hr[1]);
        hp1 = cvtpk_bf16(hr[2], hr[3]);
    };

    for (int c = 0; c < 32; ++c){
        int buf = c & 1, nbuf = buf ^ 1;
        if (c + 1 < 32) stage(nbuf);          // vmcnt wait inserted by compiler
        if (c + 2 < 32) issue_loads(c + 2);   // in flight across this chunk
        const float* fb  = &sF[buf][jm][0];
        const float* fbN = &sF[nbuf][jm][0];
        for (int th = 0; th < 32; ++th){
            int t = c*64 + 2*th;
            step(ccA, ccB, t,     fb, fbN);
            step(ccB, ccA, t + 1, fb, fbN);
        }
    }

    // ---- fc2 + softmax (h from packed bf16 — same precision the LSTM saw) ----
    float h0 = bf2f(hp0 & 0xffffu), h1 = bf2f(hp0 >> 16);
    float h2 = bf2f(hp1 & 0xffffu), h3 = bf2f(hp1 >> 16);
    float l0 = h0*fcw0[0] + h1*fcw0[1] + h2*fcw0[2] + h3*fcw0[3];
    float l1 = h0*fcw1[0] + h1*fcw1[1] + h2*fcw1[2] + h3*fcw1[3];
    l0 += __shfl_xor(l0, 16); l0 += __shfl_xor(l0, 32);
    l1 += __shfl_xor(l1, 16); l1 += __shfl_xor(l1, 32);
    if (lane < 16){
        l0 += fc2_b[0]; l1 += fc2_b[1];
        float p1 = frcp(1.f + fexp2((l0 - l1) * LOG2E));
        out[2*(b0 + lane) + 0] = 1.f - p1;
        out[2*(b0 + lane) + 1] = p1;
    }
}

extern "C" void kernel_launch(void* const* d_in, const int* in_sizes, int n_in,
                              void* d_out, int out_size, void* d_ws, size_t ws_size,
                              hipStream_t stream){
    const float* x     = (const float*)d_in[0];
    const float* fc1_w = (const float*)d_in[1];
    // d_in[2] = fc1_b: cancels out of the BN algebra, unused
    const float* bn_g  = (const float*)d_in[3];
    const float* bn_b  = (const float*)d_in[4];
    const float* w_ih  = (const float*)d_in[5];
    const float* w_hh  = (const float*)d_in[6];
    const float* b_ih  = (const float*)d_in[7];
    const float* b_hh  = (const float*)d_in[8];
    const float* fc2_w = (const float*)d_in[9];
    const float* fc2_b = (const float*)d_in[10];
    float* out = (float*)d_out;

    float* ws     = (float*)d_ws;
    float* part_s = ws;                          // 64*2048 f32
    float* part_q = ws + 64 * T_LEN;             // 64*2048 f32
    float2* AB    = (float2*)(ws + 128 * T_LEN); // 2048 float2

    k_stats<<<dim3(T_LEN / 256, 64), 256, 0, stream>>>(x, part_s, part_q);
    k_coeff<<<dim3(T_LEN / 256), 256, 0, stream>>>(part_s, part_q, fc1_w, bn_g, bn_b, AB);
    k_lstm <<<dim3(B_SZ / 16), 64, 0, stream>>>(x, AB, w_ih, w_hh, b_ih, b_hh,
                                                fc2_w, fc2_b, out);
}